// Round 18
// baseline (284.659 us; speedup 1.0000x reference)
//
#include <hip/hip_runtime.h>
#include <stdint.h>

typedef __bf16 bf16x8 __attribute__((ext_vector_type(8)));
typedef float f32x4 __attribute__((ext_vector_type(4)));
typedef unsigned short u16;
typedef unsigned int u32;

#define N_INST 50000
#define NPAD   50048   // 391 * 128 = 782 * 64
#define LIN    1024
#define D1     512
#define D2     256
#define TOPK   64
#define TDIM   49
#define NBIN   65536
#define CAND_MAX 8192
// dwords to zero: accum(520) + ids(128) + ctl(16) + hist(65536)
#define ZERO_DW (520 + 128 + 16 + NBIN)

__device__ __forceinline__ float b2f(u16 u) {
    union { float f; u32 i; } x; x.i = ((u32)u) << 16; return x.f;
}
__device__ __forceinline__ u16 f2b(float f) {
    union { float f; u32 i; } x; x.f = f;
    u32 r = x.i + 0x7FFFu + ((x.i >> 16) & 1u);   // RNE
    return (u16)(r >> 16);
}
// async global->LDS, 16B per lane. dst must be linear in lane order (wave-uniform base + lane*16).
__device__ __forceinline__ void gload16(const void* g, void* l) {
    __builtin_amdgcn_global_load_lds((const __attribute__((address_space(1))) void*)g,
                                     (__attribute__((address_space(3))) void*)l, 16, 0, 0);
}
// byte offset of a swizzled [row][64 bf16] tile element (T2 st-style XOR swizzle)
__device__ __forceinline__ u32 swz(int row, int bytecol) {
    return (u32)(row * 128 + (bytecol ^ ((row & 7) << 4)));
}

// ---------------- pack weights: W_fc -> WfcT bf16 [512][1024];
// Wa/Wb -> gate-interleaved WabT bf16 [512][512]: col 2j = Wa[:,j], col 2j+1 = Wb[:,j].
// Also zeroes the accumulator/histogram region.
__global__ void pack_w(const float* __restrict__ W_fc, const float* __restrict__ Wa,
                       const float* __restrict__ Wb, u16* __restrict__ WfcT,
                       u16* __restrict__ WabT, u32* __restrict__ zbase) {
    int gt = blockIdx.x * blockDim.x + threadIdx.x;
    int nthr = gridDim.x * blockDim.x;
    for (int z = gt; z < ZERO_DW; z += nthr) zbase[z] = 0u;
    for (int e = gt; e < D1 * LIN; e += nthr) {
        int n = e >> 10, k = e & 1023;
        WfcT[e] = f2b(W_fc[(size_t)k * D1 + n]);
    }
    for (int f = gt; f < 2 * D2 * D1; f += nthr) {
        int c = f >> 9, k = f & 511;          // B' col c, k
        int j = c >> 1;
        WabT[f] = f2b((c & 1) ? Wb[(size_t)k * D2 + j] : Wa[(size_t)k * D2 + j]);
    }
}

// ---------------- GEMM1: h512 = relu(h_fp32 @ W_fc + b_fc). R13 config (best measured):
// 2 blocks/CU via __launch_bounds__(512,4) (LDS 48 KB x2 = 96 <= 160; VGPR 64 <= cap 128).
// BM=128, BN=256, BK=64, 8 waves 2x4. A: fp32 reg-prefetch -> bf16 -> swizzled ds_write.
// B: global_load_lds w/ pre-swizzled source. All LDS reads XOR-swizzled (T2).
__global__ __launch_bounds__(512, 4)
void gemm_fc(const float* __restrict__ h, const u16* __restrict__ WfcT,
             const float* __restrict__ b_fc, u16* __restrict__ h512) {
    __shared__ __align__(16) u16 lA[128 * 64];    // 16 KB
    __shared__ __align__(16) u16 lB[256 * 64];    // 32 KB
    const int tid = threadIdx.x;
    const int lane = tid & 63, wid = tid >> 6;
    const int wr = wid >> 2, wc = wid & 3;        // 2 x 4 wave grid, 64x64 each
    const int lanelo = lane & 15, lanehi = lane >> 4;
    const int row0 = blockIdx.y * 128;
    const int col0 = blockIdx.x * 256;

    const int arow = tid >> 2;                    // 0..127
    const int aseg = tid & 3;                     // 16 floats each
    int srow = row0 + arow; if (srow >= N_INST) srow = N_INST - 1;
    const float* abase = h + (size_t)srow * LIN + aseg * 16;
    u16* aw0 = (u16*)((char*)lA + swz(arow, aseg * 32));
    u16* aw1 = (u16*)((char*)lA + swz(arow, aseg * 32 + 16));

    f32x4 acc[4][4];
    const f32x4 z4 = {0.f, 0.f, 0.f, 0.f};
    #pragma unroll
    for (int m = 0; m < 4; ++m)
        #pragma unroll
        for (int n = 0; n < 4; ++n) acc[m][n] = z4;

    float4 a0, a1, a2, a3;
    { const float4* ap = (const float4*)abase; a0 = ap[0]; a1 = ap[1]; a2 = ap[2]; a3 = ap[3]; }

    for (int kt = 0; kt < LIN / 64; ++kt) {
        #pragma unroll
        for (int q = 0; q < 4; ++q) {
            int c = tid + 512 * q;
            int col = c >> 3, d8 = c & 7;
            int k8 = d8 ^ (col & 7);
            gload16(WfcT + (size_t)(col0 + col) * LIN + kt * 64 + k8 * 8, (char*)lB + c * 16);
        }
        {
            bf16x8 w0, w1;
            w0[0] = (__bf16)a0.x; w0[1] = (__bf16)a0.y; w0[2] = (__bf16)a0.z; w0[3] = (__bf16)a0.w;
            w0[4] = (__bf16)a1.x; w0[5] = (__bf16)a1.y; w0[6] = (__bf16)a1.z; w0[7] = (__bf16)a1.w;
            w1[0] = (__bf16)a2.x; w1[1] = (__bf16)a2.y; w1[2] = (__bf16)a2.z; w1[3] = (__bf16)a2.w;
            w1[4] = (__bf16)a3.x; w1[5] = (__bf16)a3.y; w1[6] = (__bf16)a3.z; w1[7] = (__bf16)a3.w;
            *(bf16x8*)aw0 = w0;
            *(bf16x8*)aw1 = w1;
        }
        __syncthreads();
        if (kt + 1 < LIN / 64) {
            const float4* ap = (const float4*)(abase + (kt + 1) * 64);
            a0 = ap[0]; a1 = ap[1]; a2 = ap[2]; a3 = ap[3];
        }
        #pragma unroll
        for (int kk = 0; kk < 2; ++kk) {
            bf16x8 af[4], bfr[4];
            #pragma unroll
            for (int m = 0; m < 4; ++m) {
                int row = wr * 64 + m * 16 + lanelo;
                af[m] = *(const bf16x8*)((char*)lA + swz(row, kk * 64 + lanehi * 16));
            }
            #pragma unroll
            for (int n = 0; n < 4; ++n) {
                int col = wc * 64 + n * 16 + lanelo;
                bfr[n] = *(const bf16x8*)((char*)lB + swz(col, kk * 64 + lanehi * 16));
            }
            #pragma unroll
            for (int m = 0; m < 4; ++m)
                #pragma unroll
                for (int n = 0; n < 4; ++n)
                    acc[m][n] = __builtin_amdgcn_mfma_f32_16x16x32_bf16(af[m], bfr[n], acc[m][n], 0, 0, 0);
        }
        __syncthreads();
    }
    #pragma unroll
    for (int n = 0; n < 4; ++n) {
        int col = col0 + wc * 64 + n * 16 + lanelo;
        float bias = b_fc[col];
        #pragma unroll
        for (int m = 0; m < 4; ++m) {
            int rbase = row0 + wr * 64 + m * 16 + 4 * lanehi;
            #pragma unroll
            for (int r = 0; r < 4; ++r) {
                float v = acc[m][n][r] + bias;
                v = v > 0.f ? v : 0.f;
                h512[(size_t)(rbase + r) * D1 + col] = f2b(v);
            }
        }
    }
}

// ---------------- GEMM2 gate-interleaved: one GEMM [64x512]@[512x512(B')] per block.
// BM=64, BN=512(B'), BK=64, 8 waves 2x4 (wave tile 32x128): acc 2x8 = 64 VGPRs.
// LDS 8+64 = 72 KB -> 2 blocks/CU at (512,4) — fc-R13 occupancy applied to attn.
// Epilogue: cols 2j/2j+1 on adjacent lanes; shfl_xor(v,1) pairs (a_j,b_j);
// even lane contributes tanh(a)*sigmoid(b)*Wc[j] to the 16-lane reduce.
__global__ __launch_bounds__(512, 4)
void gemm_attn(const u16* __restrict__ h512, const u16* __restrict__ WabT,
               const float* __restrict__ ba, const float* __restrict__ bb,
               const float* __restrict__ Wc, const float* __restrict__ bc,
               float* __restrict__ araw, u32* __restrict__ uarr, u32* __restrict__ hist,
               float* __restrict__ Zacc, float* __restrict__ Mpart) {
    __shared__ __align__(16) u16 lA[64 * 64];      // 8 KB
    __shared__ __align__(16) u16 lB[512 * 64];     // 64 KB
    __shared__ float rsum[64];
    __shared__ float sW[64];
    const int tid = threadIdx.x;
    const int lane = tid & 63, wid = tid >> 6;
    const int wr = wid >> 2, wc4 = wid & 3;        // 2 x 4 wave grid, 32 x 128 each
    const int lanelo = lane & 15, lanehi = lane >> 4;
    const int row0 = blockIdx.x * 64;

    f32x4 acc[2][8];
    const f32x4 z4 = {0.f, 0.f, 0.f, 0.f};
    #pragma unroll
    for (int m = 0; m < 2; ++m)
        #pragma unroll
        for (int n = 0; n < 8; ++n) acc[m][n] = z4;

    for (int kt = 0; kt < D1 / 64; ++kt) {
        {   // A: 64x64 bf16 = 512 chunks, 1/thread, pre-swizzled source
            int c = tid;
            int row = c >> 3, d8 = c & 7;
            int k8 = d8 ^ (row & 7);
            gload16(h512 + (size_t)(row0 + row) * D1 + kt * 64 + k8 * 8, (char*)lA + c * 16);
        }
        #pragma unroll
        for (int q = 0; q < 8; ++q) {          // B': 512x64 = 4096 chunks, 8/thread
            int c = tid + 512 * q;
            int col = c >> 3, d8 = c & 7;
            int k8 = d8 ^ (col & 7);
            gload16(WabT + (size_t)col * D1 + kt * 64 + k8 * 8, (char*)lB + c * 16);
        }
        __syncthreads();
        #pragma unroll
        for (int kk = 0; kk < 2; ++kk) {
            bf16x8 af[2], bfr[8];
            #pragma unroll
            for (int m = 0; m < 2; ++m) {
                int row = wr * 32 + m * 16 + lanelo;
                af[m] = *(const bf16x8*)((char*)lA + swz(row, kk * 64 + lanehi * 16));
            }
            #pragma unroll
            for (int n = 0; n < 8; ++n) {
                int col = wc4 * 128 + n * 16 + lanelo;
                bfr[n] = *(const bf16x8*)((char*)lB + swz(col, kk * 64 + lanehi * 16));
            }
            #pragma unroll
            for (int m = 0; m < 2; ++m)
                #pragma unroll
                for (int n = 0; n < 8; ++n)
                    acc[m][n] = __builtin_amdgcn_mfma_f32_16x16x32_bf16(af[m], bfr[n], acc[m][n], 0, 0, 0);
        }
        __syncthreads();
    }

    if (tid < 64) rsum[tid] = 0.f;
    __syncthreads();

    // biases/Wc per n-frag: j identical for lane pair (2j,2j+1)
    float baR[8], bbR[8], wcR[8];
    #pragma unroll
    for (int n = 0; n < 8; ++n) {
        int j = (wc4 * 128 + n * 16 + lanelo) >> 1;
        baR[n] = ba[j]; bbR[n] = bb[j]; wcR[n] = Wc[j];
    }
    const bool isA = (lanelo & 1) == 0;
    #pragma unroll
    for (int m = 0; m < 2; ++m) {
        #pragma unroll
        for (int r = 0; r < 4; ++r) {
            float s = 0.f;
            #pragma unroll
            for (int n = 0; n < 8; ++n) {
                float v = acc[m][n][r];
                float o = __shfl_xor(v, 1);
                float araw_ = isA ? v : o;
                float braw_ = isA ? o : v;
                float p = tanhf(araw_ + baR[n]) / (1.f + expf(-(braw_ + bbR[n])));
                s += isA ? p * wcR[n] : 0.f;
            }
            s += __shfl_xor(s, 1); s += __shfl_xor(s, 2);
            s += __shfl_xor(s, 4); s += __shfl_xor(s, 8);
            if (lanelo == 0) atomicAdd(&rsum[wr * 32 + m * 16 + 4 * lanehi + r], s);
        }
    }
    __syncthreads();

    if (tid < 64) {
        int rg = row0 + tid;
        float e = 0.f;
        if (rg < N_INST) {
            float a = rsum[tid] + bc[0];
            araw[rg] = a;
            u32 bits = __float_as_uint(a);
            u32 key = (bits & 0x80000000u) ? ~bits : (bits | 0x80000000u);
            uarr[rg] = key;
            atomicAdd(&hist[key >> 16], 1u);
            e = expf(a);
        }
        sW[tid] = e;
    }
    __syncthreads();
    if (tid < 64) {                            // wave 0 butterfly over 64 lanes
        float e = sW[tid];
        for (int o = 32; o > 0; o >>= 1) e += __shfl_xor(e, o);
        if (lane == 0) atomicAdd(Zacc, e);
    }
    // M partial: 64 rows x 512 cols, one col per thread (coalesced, L2-hot)
    float accM = 0.f;
    #pragma unroll 8
    for (int i = 0; i < 64; ++i)
        accM += sW[i] * b2f(h512[(size_t)(row0 + i) * D1 + tid]);
    atomicAdd(&Mpart[tid], accM);
}

// ---------------- topk collect with inline hist scan (every block computes boundaries)
__global__ void topk_collect(const u32* __restrict__ hist, const u32* __restrict__ uarr,
                             int* __restrict__ ctl, int* __restrict__ ids,
                             u32* __restrict__ cV0, int* __restrict__ cI0,
                             u32* __restrict__ cV1, int* __restrict__ cI1) {
    __shared__ int part[256];
    __shared__ int sp0, sb0, sp1, sb1;
    const int t = threadIdx.x;                 // 256
    const uint4* h4 = (const uint4*)hist;
    int s = 0;
    for (int j = 0; j < 64; ++j) {
        uint4 v = h4[t * 64 + j];
        s += (int)(v.x + v.y + v.z + v.w);
    }
    part[t] = s;
    __syncthreads();
    for (int off = 1; off < 256; off <<= 1) {
        int v = part[t];
        int a = (t >= off) ? part[t - off] : 0;
        __syncthreads();
        part[t] = v + a;
        __syncthreads();
    }
    int run = part[t] - s;
    for (int j = 0; j < 64; ++j) {
        uint4 v = h4[t * 64 + j];
        int c4[4]; c4[0] = (int)v.x; c4[1] = (int)v.y; c4[2] = (int)v.z; c4[3] = (int)v.w;
        #pragma unroll
        for (int e = 0; e < 4; ++e) {
            int cnt = c4[e];
            if (cnt > 0) {
                int b = t * 256 + j * 4 + e;
                int less = run, greater = N_INST - run - cnt;
                if (greater < TOPK && greater + cnt >= TOPK) { sp0 = b; sb0 = greater; }
                if (less < TOPK && less + cnt >= TOPK)       { sp1 = b; sb1 = less; }
            }
            run += cnt;
        }
    }
    __syncthreads();
    const int p0 = sp0, p1 = sp1;
    if (blockIdx.x == 0 && t == 0) { ctl[0] = sp0; ctl[1] = sb0; ctl[2] = sp1; ctl[3] = sb1; }

    int gt = blockIdx.x * blockDim.x + t;
    int nthr = gridDim.x * blockDim.x;
    for (int i = gt; i < N_INST; i += nthr) {
        u32 v = uarr[i];
        int b = (int)(v >> 16);
        if (b > p0)       { int p = atomicAdd(&ctl[8], 1);  ids[p] = i; }
        else if (b == p0) { int p = atomicAdd(&ctl[9], 1);  if (p < CAND_MAX) { cV0[p] = v; cI0[p] = i; } }
        if (b < p1)       { int p = atomicAdd(&ctl[10], 1); ids[TOPK + p] = i; }
        else if (b == p1) { int p = atomicAdd(&ctl[11], 1); if (p < CAND_MAX) { cV1[p] = v; cI1[p] = i; } }
    }
}

// ---------------- tail: topk finish + instance CE loss + final head (one block, 256 thr)
__global__ void tail_fused(const int* __restrict__ ctl,
                           const u32* __restrict__ cV0, const int* __restrict__ cI0,
                           const u32* __restrict__ cV1, const int* __restrict__ cI1,
                           int* __restrict__ ids, const u16* __restrict__ h512,
                           const float* __restrict__ W_inst, const float* __restrict__ b_inst,
                           const int* __restrict__ label, const float* __restrict__ Mpart,
                           const float* __restrict__ Zacc, const float* __restrict__ tabular,
                           const float* __restrict__ W_img, const float* __restrict__ b_img,
                           const float* __restrict__ W_tab, const float* __restrict__ b_tab,
                           const float* __restrict__ W_cls, const float* __restrict__ b_cls,
                           float* __restrict__ d_out) {
    __shared__ int h8[256];
    __shared__ int eq[2048];
    __shared__ int s_d1, s_k1, s_d2, s_fill, s_eqc;
    __shared__ float lsum;
    __shared__ float sM[512];
    __shared__ float stab[TDIM];
    __shared__ float red0[256], red1[256];
    __shared__ float simg;
    const int tid = threadIdx.x;               // 256
    const int lane = tid & 63, wid = tid >> 6;

    for (int mode = 0; mode < 2; ++mode) {
        int basem = ctl[mode * 2 + 1];
        int need = TOPK - basem;
        int ccnt = ctl[9 + mode * 2];
        if (ccnt > CAND_MAX) ccnt = CAND_MAX;
        const u32* cV = mode ? cV1 : cV0;
        const int* cI = mode ? cI1 : cI0;
        int* dst = ids + mode * TOPK;
        h8[tid] = 0; __syncthreads();
        for (int i = tid; i < ccnt; i += 256) atomicAdd(&h8[(cV[i] >> 8) & 255u], 1);
        __syncthreads();
        if (tid == 0) {
            int acc = 0, d, k = need;
            if (mode == 0) { for (d = 255; d >= 0; --d) { acc += h8[d]; if (acc >= k) break; } }
            else           { for (d = 0; d < 256; ++d)  { acc += h8[d]; if (acc >= k) break; } }
            s_d1 = d; s_k1 = k - (acc - h8[d]);
        }
        __syncthreads();
        int d1 = s_d1, k1 = s_k1;
        h8[tid] = 0; __syncthreads();
        for (int i = tid; i < ccnt; i += 256) {
            u32 v = cV[i];
            if (((v >> 8) & 255u) == (u32)d1) atomicAdd(&h8[v & 255u], 1);
        }
        __syncthreads();
        if (tid == 0) {
            int acc = 0, d, k = k1;
            if (mode == 0) { for (d = 255; d >= 0; --d) { acc += h8[d]; if (acc >= k) break; } }
            else           { for (d = 0; d < 256; ++d)  { acc += h8[d]; if (acc >= k) break; } }
            s_d2 = d; s_fill = 0; s_eqc = 0;
        }
        __syncthreads();
        u32 vth = ((u32)ctl[mode * 2] << 16) | ((u32)d1 << 8) | (u32)s_d2;
        for (int i = tid; i < ccnt; i += 256) {
            u32 v = cV[i];
            bool better = mode == 0 ? (v > vth) : (v < vth);
            if (better)        { int p = atomicAdd(&s_fill, 1); dst[basem + p] = cI[i]; }
            else if (v == vth) { int p = atomicAdd(&s_eqc, 1);  if (p < 2048) eq[p] = cI[i]; }
        }
        __syncthreads();
        if (tid == 0) {
            int have = basem + s_fill;
            int rem = TOPK - have;
            int m = s_eqc < 2048 ? s_eqc : 2048;
            int last = -1;
            for (int q = 0; q < rem; ++q) {
                int best = 0x7FFFFFFF;
                for (int s = 0; s < m; ++s) { int ix = eq[s]; if (ix > last && ix < best) best = ix; }
                dst[have + q] = best; last = best;
            }
        }
        __syncthreads();
    }

    if (tid == 0) lsum = 0.f;
    __syncthreads();
    const int lab = label[0];
    const float* W = W_inst + (size_t)lab * (D1 * 2);
    const float b0 = b_inst[lab * 2 + 0], b1 = b_inst[lab * 2 + 1];
    for (int i = 0; i < 32; ++i) {
        int r = wid * 32 + i;
        int row = ids[r];
        float s0 = 0.f, s1 = 0.f;
        for (int s = 0; s < 8; ++s) {
            int j = lane + 64 * s;
            float hv = b2f(h512[(size_t)row * D1 + j]);
            s0 += hv * W[j * 2 + 0];
            s1 += hv * W[j * 2 + 1];
        }
        for (int o = 32; o > 0; o >>= 1) { s0 += __shfl_xor(s0, o); s1 += __shfl_xor(s1, o); }
        if (lane == 0) {
            float l0 = s0 + b0, l1 = s1 + b1;
            float mx = fmaxf(l0, l1);
            float lse = mx + logf(expf(l0 - mx) + expf(l1 - mx));
            float lt = (r < TOPK) ? l1 : l0;
            atomicAdd(&lsum, lse - lt);
        }
    }
    __syncthreads();
    if (tid == 0) d_out[50005] = lsum / 128.f;

    float invZ = 1.f / Zacc[0];
    sM[tid] = Mpart[tid] * invZ;
    sM[tid + 256] = Mpart[tid + 256] * invZ;
    red0[tid] = sM[tid] * W_img[tid] + sM[tid + 256] * W_img[tid + 256];
    __syncthreads();
    for (int o = 128; o > 0; o >>= 1) { if (tid < o) red0[tid] += red0[tid + o]; __syncthreads(); }
    if (tid == 0) simg = 1.f / (1.f + expf(-(red0[0] + b_img[0])));
    if (tid < TDIM) {
        float t = b_tab[tid];
        for (int kx = 0; kx < TDIM; ++kx) t += tabular[kx] * W_tab[kx * TDIM + tid];
        stab[tid] = t;
    }
    __syncthreads();
    if (tid == 0) {
        float mx = stab[0];
        for (int o = 1; o < TDIM; ++o) mx = fmaxf(mx, stab[o]);
        float ss = 0.f;
        for (int o = 0; o < TDIM; ++o) { float e = expf(stab[o] - mx); stab[o] = e; ss += e; }
        for (int o = 0; o < TDIM; ++o) stab[o] = (stab[o] / ss) * tabular[o];
    }
    __syncthreads();
    float img = simg;
    float a0 = 0.f, a1 = 0.f;
    for (int j = tid; j < D1 + TDIM; j += 256) {
        float w = (j < D1) ? img * sM[j] : stab[j - D1];
        a0 += w * W_cls[j * 2 + 0];
        a1 += w * W_cls[j * 2 + 1];
    }
    red0[tid] = a0; red1[tid] = a1;
    __syncthreads();
    for (int o = 128; o > 0; o >>= 1) {
        if (tid < o) { red0[tid] += red0[tid + o]; red1[tid] += red1[tid + o]; }
        __syncthreads();
    }
    if (tid == 0) {
        float l0 = red0[0] + b_cls[0];
        float l1 = red1[0] + b_cls[1];
        d_out[0] = l0; d_out[1] = l1;
        float mx = fmaxf(l0, l1);
        float e0 = expf(l0 - mx), e1 = expf(l1 - mx);
        d_out[2] = e0 / (e0 + e1);
        d_out[3] = e1 / (e0 + e1);
        d_out[4] = (l1 > l0) ? 1.f : 0.f;
    }
}

extern "C" void kernel_launch(void* const* d_in, const int* in_sizes, int n_in,
                              void* d_out, int out_size, void* d_ws, size_t ws_size,
                              hipStream_t stream) {
    const float* h       = (const float*)d_in[0];
    const float* tabular = (const float*)d_in[1];
    const int*   label   = (const int*)d_in[2];
    const float* W_fc    = (const float*)d_in[3];
    const float* b_fc    = (const float*)d_in[4];
    const float* Wa      = (const float*)d_in[5];
    const float* ba      = (const float*)d_in[6];
    const float* Wb      = (const float*)d_in[7];
    const float* bb      = (const float*)d_in[8];
    const float* Wc      = (const float*)d_in[9];
    const float* bc      = (const float*)d_in[10];
    const float* W_inst  = (const float*)d_in[11];
    const float* b_inst  = (const float*)d_in[12];
    const float* W_img   = (const float*)d_in[13];
    const float* b_img   = (const float*)d_in[14];
    const float* W_tab   = (const float*)d_in[15];
    const float* b_tab   = (const float*)d_in[16];
    const float* W_cls   = (const float*)d_in[17];
    const float* b_cls   = (const float*)d_in[18];
    float* out = (float*)d_out;

    // workspace layout (~53 MB)
    u16* h512 = (u16*)d_ws;                          // NPAD x 512 bf16      (51.2 MB)
    u16* WfcT = h512 + (size_t)NPAD * D1;            // 512 x 1024 bf16      (1 MB)
    u16* WabT = WfcT + (size_t)D1 * LIN;             // 512 x 512 bf16 (gate-interleaved)
    u32* uarr = (u32*)(WabT + (size_t)2 * D2 * D1);  // NPAD sortable keys
    float* accum = (float*)(uarr + NPAD);            // [0]=Z, [8..520)=Mpart
    float* Zacc  = accum;
    float* Mpart = accum + 8;
    int* ids = (int*)(accum + 8 + D1);               // 128 selected indices
    int* ctl = ids + 128;                            // 16 ints: buckets+counters
    u32* hist = (u32*)(ctl + 16);                    // 65536 bins
    u32* cV0 = hist + NBIN;
    int* cI0 = (int*)(cV0 + CAND_MAX);
    u32* cV1 = (u32*)(cI0 + CAND_MAX);
    int* cI1 = (int*)(cV1 + CAND_MAX);

    pack_w<<<dim3(256), dim3(256), 0, stream>>>(W_fc, Wa, Wb, WfcT, WabT, (u32*)accum);
    gemm_fc<<<dim3(2, NPAD / 128), dim3(512), 0, stream>>>(h, WfcT, b_fc, h512);
    gemm_attn<<<dim3(NPAD / 64), dim3(512), 0, stream>>>(
        h512, WabT, ba, bb, Wc, bc, out + 5, uarr, hist, Zacc, Mpart);
    topk_collect<<<dim3(128), dim3(256), 0, stream>>>(hist, uarr, ctl, ids, cV0, cI0, cV1, cI1);
    tail_fused<<<dim3(1), dim3(256), 0, stream>>>(
        ctl, cV0, cI0, cV1, cI1, ids, h512, W_inst, b_inst, label,
        Mpart, Zacc, tabular, W_img, b_img, W_tab, b_tab, W_cls, b_cls, out);
}

// Round 19
// 282.503 us; speedup vs baseline: 1.0076x; 1.0076x over previous
//
#include <hip/hip_runtime.h>
#include <stdint.h>

typedef __bf16 bf16x8 __attribute__((ext_vector_type(8)));
typedef float f32x4 __attribute__((ext_vector_type(4)));
typedef unsigned short u16;
typedef unsigned int u32;

#define N_INST 50000
#define NPAD   50048   // 391 * 128 = 782 * 64
#define LIN    1024
#define D1     512
#define D2     256
#define TOPK   64
#define TDIM   49
#define NBIN   65536
#define CAND_MAX 8192
// dwords to zero: accum(520) + ids(128) + ctl(16) + hist(65536)
#define ZERO_DW (520 + 128 + 16 + NBIN)

__device__ __forceinline__ float b2f(u16 u) {
    union { float f; u32 i; } x; x.i = ((u32)u) << 16; return x.f;
}
__device__ __forceinline__ u16 f2b(float f) {
    union { float f; u32 i; } x; x.f = f;
    u32 r = x.i + 0x7FFFu + ((x.i >> 16) & 1u);   // RNE
    return (u16)(r >> 16);
}
// async global->LDS, 16B per lane. dst must be linear in lane order (wave-uniform base + lane*16).
__device__ __forceinline__ void gload16(const void* g, void* l) {
    __builtin_amdgcn_global_load_lds((const __attribute__((address_space(1))) void*)g,
                                     (__attribute__((address_space(3))) void*)l, 16, 0, 0);
}
// byte offset of a swizzled [row][64 bf16] tile element (T2 st-style XOR swizzle)
__device__ __forceinline__ u32 swz(int row, int bytecol) {
    return (u32)(row * 128 + (bytecol ^ ((row & 7) << 4)));
}

// ---------------- pack weights: W_fc -> WfcT bf16 [512][1024];
// Wa/Wb -> gate-interleaved WabT bf16 [512][512]: col 2j = Wa[:,j], col 2j+1 = Wb[:,j].
// Also zeroes the accumulator/histogram region.
__global__ void pack_w(const float* __restrict__ W_fc, const float* __restrict__ Wa,
                       const float* __restrict__ Wb, u16* __restrict__ WfcT,
                       u16* __restrict__ WabT, u32* __restrict__ zbase) {
    int gt = blockIdx.x * blockDim.x + threadIdx.x;
    int nthr = gridDim.x * blockDim.x;
    for (int z = gt; z < ZERO_DW; z += nthr) zbase[z] = 0u;
    for (int e = gt; e < D1 * LIN; e += nthr) {
        int n = e >> 10, k = e & 1023;
        WfcT[e] = f2b(W_fc[(size_t)k * D1 + n]);
    }
    for (int f = gt; f < 2 * D2 * D1; f += nthr) {
        int c = f >> 9, k = f & 511;          // B' col c, k
        int j = c >> 1;
        WabT[f] = f2b((c & 1) ? Wb[(size_t)k * D2 + j] : Wa[(size_t)k * D2 + j]);
    }
}

// ---------------- GEMM1: h512 = relu(h_fp32 @ W_fc + b_fc). R13 config (best measured):
// 2 blocks/CU via __launch_bounds__(512,4) (LDS 48 KB x2 = 96 <= 160; VGPR 64 <= cap 128).
// BM=128, BN=256, BK=64, 8 waves 2x4. A: fp32 reg-prefetch -> bf16 -> swizzled ds_write.
// B: global_load_lds w/ pre-swizzled source. All LDS reads XOR-swizzled (T2).
__global__ __launch_bounds__(512, 4)
void gemm_fc(const float* __restrict__ h, const u16* __restrict__ WfcT,
             const float* __restrict__ b_fc, u16* __restrict__ h512) {
    __shared__ __align__(16) u16 lA[128 * 64];    // 16 KB
    __shared__ __align__(16) u16 lB[256 * 64];    // 32 KB
    const int tid = threadIdx.x;
    const int lane = tid & 63, wid = tid >> 6;
    const int wr = wid >> 2, wc = wid & 3;        // 2 x 4 wave grid, 64x64 each
    const int lanelo = lane & 15, lanehi = lane >> 4;
    const int row0 = blockIdx.y * 128;
    const int col0 = blockIdx.x * 256;

    const int arow = tid >> 2;                    // 0..127
    const int aseg = tid & 3;                     // 16 floats each
    int srow = row0 + arow; if (srow >= N_INST) srow = N_INST - 1;
    const float* abase = h + (size_t)srow * LIN + aseg * 16;
    u16* aw0 = (u16*)((char*)lA + swz(arow, aseg * 32));
    u16* aw1 = (u16*)((char*)lA + swz(arow, aseg * 32 + 16));

    f32x4 acc[4][4];
    const f32x4 z4 = {0.f, 0.f, 0.f, 0.f};
    #pragma unroll
    for (int m = 0; m < 4; ++m)
        #pragma unroll
        for (int n = 0; n < 4; ++n) acc[m][n] = z4;

    float4 a0, a1, a2, a3;
    { const float4* ap = (const float4*)abase; a0 = ap[0]; a1 = ap[1]; a2 = ap[2]; a3 = ap[3]; }

    for (int kt = 0; kt < LIN / 64; ++kt) {
        #pragma unroll
        for (int q = 0; q < 4; ++q) {
            int c = tid + 512 * q;
            int col = c >> 3, d8 = c & 7;
            int k8 = d8 ^ (col & 7);
            gload16(WfcT + (size_t)(col0 + col) * LIN + kt * 64 + k8 * 8, (char*)lB + c * 16);
        }
        {
            bf16x8 w0, w1;
            w0[0] = (__bf16)a0.x; w0[1] = (__bf16)a0.y; w0[2] = (__bf16)a0.z; w0[3] = (__bf16)a0.w;
            w0[4] = (__bf16)a1.x; w0[5] = (__bf16)a1.y; w0[6] = (__bf16)a1.z; w0[7] = (__bf16)a1.w;
            w1[0] = (__bf16)a2.x; w1[1] = (__bf16)a2.y; w1[2] = (__bf16)a2.z; w1[3] = (__bf16)a2.w;
            w1[4] = (__bf16)a3.x; w1[5] = (__bf16)a3.y; w1[6] = (__bf16)a3.z; w1[7] = (__bf16)a3.w;
            *(bf16x8*)aw0 = w0;
            *(bf16x8*)aw1 = w1;
        }
        __syncthreads();
        if (kt + 1 < LIN / 64) {
            const float4* ap = (const float4*)(abase + (kt + 1) * 64);
            a0 = ap[0]; a1 = ap[1]; a2 = ap[2]; a3 = ap[3];
        }
        #pragma unroll
        for (int kk = 0; kk < 2; ++kk) {
            bf16x8 af[4], bfr[4];
            #pragma unroll
            for (int m = 0; m < 4; ++m) {
                int row = wr * 64 + m * 16 + lanelo;
                af[m] = *(const bf16x8*)((char*)lA + swz(row, kk * 64 + lanehi * 16));
            }
            #pragma unroll
            for (int n = 0; n < 4; ++n) {
                int col = wc * 64 + n * 16 + lanelo;
                bfr[n] = *(const bf16x8*)((char*)lB + swz(col, kk * 64 + lanehi * 16));
            }
            #pragma unroll
            for (int m = 0; m < 4; ++m)
                #pragma unroll
                for (int n = 0; n < 4; ++n)
                    acc[m][n] = __builtin_amdgcn_mfma_f32_16x16x32_bf16(af[m], bfr[n], acc[m][n], 0, 0, 0);
        }
        __syncthreads();
    }
    #pragma unroll
    for (int n = 0; n < 4; ++n) {
        int col = col0 + wc * 64 + n * 16 + lanelo;
        float bias = b_fc[col];
        #pragma unroll
        for (int m = 0; m < 4; ++m) {
            int rbase = row0 + wr * 64 + m * 16 + 4 * lanehi;
            #pragma unroll
            for (int r = 0; r < 4; ++r) {
                float v = acc[m][n][r] + bias;
                v = v > 0.f ? v : 0.f;
                h512[(size_t)(rbase + r) * D1 + col] = f2b(v);
            }
        }
    }
}

// ---------------- GEMM2 gate-interleaved: one GEMM [64x512]@[512x512(B')] per block.
// BM=64, BN=512(B'), BK=64, 8 waves 2x4 (wave tile 32x128): acc 2x8 = 64 VGPRs.
// LDS 8+64 = 72 KB -> 2 blocks/CU at (512,4).
// Epilogue uses hardware-exp transcendentals: tanh(x)=(e^2x-1)/(e^2x+1), sigmoid via __expf
// (values bounded |x|<~5 analytically; libm tanhf's branchy path was the VALU tail).
__global__ __launch_bounds__(512, 4)
void gemm_attn(const u16* __restrict__ h512, const u16* __restrict__ WabT,
               const float* __restrict__ ba, const float* __restrict__ bb,
               const float* __restrict__ Wc, const float* __restrict__ bc,
               float* __restrict__ araw, u32* __restrict__ uarr, u32* __restrict__ hist,
               float* __restrict__ Zacc, float* __restrict__ Mpart) {
    __shared__ __align__(16) u16 lA[64 * 64];      // 8 KB
    __shared__ __align__(16) u16 lB[512 * 64];     // 64 KB
    __shared__ float rsum[64];
    __shared__ float sW[64];
    const int tid = threadIdx.x;
    const int lane = tid & 63, wid = tid >> 6;
    const int wr = wid >> 2, wc4 = wid & 3;        // 2 x 4 wave grid, 32 x 128 each
    const int lanelo = lane & 15, lanehi = lane >> 4;
    const int row0 = blockIdx.x * 64;

    f32x4 acc[2][8];
    const f32x4 z4 = {0.f, 0.f, 0.f, 0.f};
    #pragma unroll
    for (int m = 0; m < 2; ++m)
        #pragma unroll
        for (int n = 0; n < 8; ++n) acc[m][n] = z4;

    for (int kt = 0; kt < D1 / 64; ++kt) {
        {   // A: 64x64 bf16 = 512 chunks, 1/thread, pre-swizzled source
            int c = tid;
            int row = c >> 3, d8 = c & 7;
            int k8 = d8 ^ (row & 7);
            gload16(h512 + (size_t)(row0 + row) * D1 + kt * 64 + k8 * 8, (char*)lA + c * 16);
        }
        #pragma unroll
        for (int q = 0; q < 8; ++q) {          // B': 512x64 = 4096 chunks, 8/thread
            int c = tid + 512 * q;
            int col = c >> 3, d8 = c & 7;
            int k8 = d8 ^ (col & 7);
            gload16(WabT + (size_t)col * D1 + kt * 64 + k8 * 8, (char*)lB + c * 16);
        }
        __syncthreads();
        #pragma unroll
        for (int kk = 0; kk < 2; ++kk) {
            bf16x8 af[2], bfr[8];
            #pragma unroll
            for (int m = 0; m < 2; ++m) {
                int row = wr * 32 + m * 16 + lanelo;
                af[m] = *(const bf16x8*)((char*)lA + swz(row, kk * 64 + lanehi * 16));
            }
            #pragma unroll
            for (int n = 0; n < 8; ++n) {
                int col = wc4 * 128 + n * 16 + lanelo;
                bfr[n] = *(const bf16x8*)((char*)lB + swz(col, kk * 64 + lanehi * 16));
            }
            #pragma unroll
            for (int m = 0; m < 2; ++m)
                #pragma unroll
                for (int n = 0; n < 8; ++n)
                    acc[m][n] = __builtin_amdgcn_mfma_f32_16x16x32_bf16(af[m], bfr[n], acc[m][n], 0, 0, 0);
        }
        __syncthreads();
    }

    if (tid < 64) rsum[tid] = 0.f;
    __syncthreads();

    // biases/Wc per n-frag: j identical for lane pair (2j,2j+1)
    float baR[8], bbR[8], wcR[8];
    #pragma unroll
    for (int n = 0; n < 8; ++n) {
        int j = (wc4 * 128 + n * 16 + lanelo) >> 1;
        baR[n] = ba[j]; bbR[n] = bb[j]; wcR[n] = Wc[j];
    }
    const bool isA = (lanelo & 1) == 0;
    #pragma unroll
    for (int m = 0; m < 2; ++m) {
        #pragma unroll
        for (int r = 0; r < 4; ++r) {
            float s = 0.f;
            #pragma unroll
            for (int n = 0; n < 8; ++n) {
                float v = acc[m][n][r];
                float o = __shfl_xor(v, 1);
                float ar = (isA ? v : o) + baR[n];
                float br = (isA ? o : v) + bbR[n];
                float e2 = __expf(2.f * ar);                // tanh via hw exp
                float th = (e2 - 1.f) / (e2 + 1.f);
                float sg = 1.f / (1.f + __expf(-br));       // sigmoid via hw exp
                s += isA ? th * sg * wcR[n] : 0.f;
            }
            s += __shfl_xor(s, 1); s += __shfl_xor(s, 2);
            s += __shfl_xor(s, 4); s += __shfl_xor(s, 8);
            if (lanelo == 0) atomicAdd(&rsum[wr * 32 + m * 16 + 4 * lanehi + r], s);
        }
    }
    __syncthreads();

    if (tid < 64) {
        int rg = row0 + tid;
        float e = 0.f;
        if (rg < N_INST) {
            float a = rsum[tid] + bc[0];
            araw[rg] = a;
            u32 bits = __float_as_uint(a);
            u32 key = (bits & 0x80000000u) ? ~bits : (bits | 0x80000000u);
            uarr[rg] = key;
            atomicAdd(&hist[key >> 16], 1u);
            e = __expf(a);                     // |a| small analytically; hw exp within tol
        }
        sW[tid] = e;
    }
    __syncthreads();
    if (tid < 64) {                            // wave 0 butterfly over 64 lanes
        float e = sW[tid];
        for (int o = 32; o > 0; o >>= 1) e += __shfl_xor(e, o);
        if (lane == 0) atomicAdd(Zacc, e);
    }
    // M partial: 64 rows x 512 cols, one col per thread (coalesced, L2-hot)
    float accM = 0.f;
    #pragma unroll 8
    for (int i = 0; i < 64; ++i)
        accM += sW[i] * b2f(h512[(size_t)(row0 + i) * D1 + tid]);
    atomicAdd(&Mpart[tid], accM);
}

// ---------------- topk collect with inline hist scan (every block computes boundaries)
__global__ void topk_collect(const u32* __restrict__ hist, const u32* __restrict__ uarr,
                             int* __restrict__ ctl, int* __restrict__ ids,
                             u32* __restrict__ cV0, int* __restrict__ cI0,
                             u32* __restrict__ cV1, int* __restrict__ cI1) {
    __shared__ int part[256];
    __shared__ int sp0, sb0, sp1, sb1;
    const int t = threadIdx.x;                 // 256
    const uint4* h4 = (const uint4*)hist;
    int s = 0;
    for (int j = 0; j < 64; ++j) {
        uint4 v = h4[t * 64 + j];
        s += (int)(v.x + v.y + v.z + v.w);
    }
    part[t] = s;
    __syncthreads();
    for (int off = 1; off < 256; off <<= 1) {
        int v = part[t];
        int a = (t >= off) ? part[t - off] : 0;
        __syncthreads();
        part[t] = v + a;
        __syncthreads();
    }
    int run = part[t] - s;
    for (int j = 0; j < 64; ++j) {
        uint4 v = h4[t * 64 + j];
        int c4[4]; c4[0] = (int)v.x; c4[1] = (int)v.y; c4[2] = (int)v.z; c4[3] = (int)v.w;
        #pragma unroll
        for (int e = 0; e < 4; ++e) {
            int cnt = c4[e];
            if (cnt > 0) {
                int b = t * 256 + j * 4 + e;
                int less = run, greater = N_INST - run - cnt;
                if (greater < TOPK && greater + cnt >= TOPK) { sp0 = b; sb0 = greater; }
                if (less < TOPK && less + cnt >= TOPK)       { sp1 = b; sb1 = less; }
            }
            run += cnt;
        }
    }
    __syncthreads();
    const int p0 = sp0, p1 = sp1;
    if (blockIdx.x == 0 && t == 0) { ctl[0] = sp0; ctl[1] = sb0; ctl[2] = sp1; ctl[3] = sb1; }

    int gt = blockIdx.x * blockDim.x + t;
    int nthr = gridDim.x * blockDim.x;
    for (int i = gt; i < N_INST; i += nthr) {
        u32 v = uarr[i];
        int b = (int)(v >> 16);
        if (b > p0)       { int p = atomicAdd(&ctl[8], 1);  ids[p] = i; }
        else if (b == p0) { int p = atomicAdd(&ctl[9], 1);  if (p < CAND_MAX) { cV0[p] = v; cI0[p] = i; } }
        if (b < p1)       { int p = atomicAdd(&ctl[10], 1); ids[TOPK + p] = i; }
        else if (b == p1) { int p = atomicAdd(&ctl[11], 1); if (p < CAND_MAX) { cV1[p] = v; cI1[p] = i; } }
    }
}

// ---------------- tail: topk finish + instance CE loss + final head (one block, 256 thr)
__global__ void tail_fused(const int* __restrict__ ctl,
                           const u32* __restrict__ cV0, const int* __restrict__ cI0,
                           const u32* __restrict__ cV1, const int* __restrict__ cI1,
                           int* __restrict__ ids, const u16* __restrict__ h512,
                           const float* __restrict__ W_inst, const float* __restrict__ b_inst,
                           const int* __restrict__ label, const float* __restrict__ Mpart,
                           const float* __restrict__ Zacc, const float* __restrict__ tabular,
                           const float* __restrict__ W_img, const float* __restrict__ b_img,
                           const float* __restrict__ W_tab, const float* __restrict__ b_tab,
                           const float* __restrict__ W_cls, const float* __restrict__ b_cls,
                           float* __restrict__ d_out) {
    __shared__ int h8[256];
    __shared__ int eq[2048];
    __shared__ int s_d1, s_k1, s_d2, s_fill, s_eqc;
    __shared__ float lsum;
    __shared__ float sM[512];
    __shared__ float stab[TDIM];
    __shared__ float red0[256], red1[256];
    __shared__ float simg;
    const int tid = threadIdx.x;               // 256
    const int lane = tid & 63, wid = tid >> 6;

    for (int mode = 0; mode < 2; ++mode) {
        int basem = ctl[mode * 2 + 1];
        int need = TOPK - basem;
        int ccnt = ctl[9 + mode * 2];
        if (ccnt > CAND_MAX) ccnt = CAND_MAX;
        const u32* cV = mode ? cV1 : cV0;
        const int* cI = mode ? cI1 : cI0;
        int* dst = ids + mode * TOPK;
        h8[tid] = 0; __syncthreads();
        for (int i = tid; i < ccnt; i += 256) atomicAdd(&h8[(cV[i] >> 8) & 255u], 1);
        __syncthreads();
        if (tid == 0) {
            int acc = 0, d, k = need;
            if (mode == 0) { for (d = 255; d >= 0; --d) { acc += h8[d]; if (acc >= k) break; } }
            else           { for (d = 0; d < 256; ++d)  { acc += h8[d]; if (acc >= k) break; } }
            s_d1 = d; s_k1 = k - (acc - h8[d]);
        }
        __syncthreads();
        int d1 = s_d1, k1 = s_k1;
        h8[tid] = 0; __syncthreads();
        for (int i = tid; i < ccnt; i += 256) {
            u32 v = cV[i];
            if (((v >> 8) & 255u) == (u32)d1) atomicAdd(&h8[v & 255u], 1);
        }
        __syncthreads();
        if (tid == 0) {
            int acc = 0, d, k = k1;
            if (mode == 0) { for (d = 255; d >= 0; --d) { acc += h8[d]; if (acc >= k) break; } }
            else           { for (d = 0; d < 256; ++d)  { acc += h8[d]; if (acc >= k) break; } }
            s_d2 = d; s_fill = 0; s_eqc = 0;
        }
        __syncthreads();
        u32 vth = ((u32)ctl[mode * 2] << 16) | ((u32)d1 << 8) | (u32)s_d2;
        for (int i = tid; i < ccnt; i += 256) {
            u32 v = cV[i];
            bool better = mode == 0 ? (v > vth) : (v < vth);
            if (better)        { int p = atomicAdd(&s_fill, 1); dst[basem + p] = cI[i]; }
            else if (v == vth) { int p = atomicAdd(&s_eqc, 1);  if (p < 2048) eq[p] = cI[i]; }
        }
        __syncthreads();
        if (tid == 0) {
            int have = basem + s_fill;
            int rem = TOPK - have;
            int m = s_eqc < 2048 ? s_eqc : 2048;
            int last = -1;
            for (int q = 0; q < rem; ++q) {
                int best = 0x7FFFFFFF;
                for (int s = 0; s < m; ++s) { int ix = eq[s]; if (ix > last && ix < best) best = ix; }
                dst[have + q] = best; last = best;
            }
        }
        __syncthreads();
    }

    if (tid == 0) lsum = 0.f;
    __syncthreads();
    const int lab = label[0];
    const float* W = W_inst + (size_t)lab * (D1 * 2);
    const float b0 = b_inst[lab * 2 + 0], b1 = b_inst[lab * 2 + 1];
    for (int i = 0; i < 32; ++i) {
        int r = wid * 32 + i;
        int row = ids[r];
        float s0 = 0.f, s1 = 0.f;
        for (int s = 0; s < 8; ++s) {
            int j = lane + 64 * s;
            float hv = b2f(h512[(size_t)row * D1 + j]);
            s0 += hv * W[j * 2 + 0];
            s1 += hv * W[j * 2 + 1];
        }
        for (int o = 32; o > 0; o >>= 1) { s0 += __shfl_xor(s0, o); s1 += __shfl_xor(s1, o); }
        if (lane == 0) {
            float l0 = s0 + b0, l1 = s1 + b1;
            float mx = fmaxf(l0, l1);
            float lse = mx + logf(expf(l0 - mx) + expf(l1 - mx));
            float lt = (r < TOPK) ? l1 : l0;
            atomicAdd(&lsum, lse - lt);
        }
    }
    __syncthreads();
    if (tid == 0) d_out[50005] = lsum / 128.f;

    float invZ = 1.f / Zacc[0];
    sM[tid] = Mpart[tid] * invZ;
    sM[tid + 256] = Mpart[tid + 256] * invZ;
    red0[tid] = sM[tid] * W_img[tid] + sM[tid + 256] * W_img[tid + 256];
    __syncthreads();
    for (int o = 128; o > 0; o >>= 1) { if (tid < o) red0[tid] += red0[tid + o]; __syncthreads(); }
    if (tid == 0) simg = 1.f / (1.f + expf(-(red0[0] + b_img[0])));
    if (tid < TDIM) {
        float t = b_tab[tid];
        for (int kx = 0; kx < TDIM; ++kx) t += tabular[kx] * W_tab[kx * TDIM + tid];
        stab[tid] = t;
    }
    __syncthreads();
    if (tid == 0) {
        float mx = stab[0];
        for (int o = 1; o < TDIM; ++o) mx = fmaxf(mx, stab[o]);
        float ss = 0.f;
        for (int o = 0; o < TDIM; ++o) { float e = expf(stab[o] - mx); stab[o] = e; ss += e; }
        for (int o = 0; o < TDIM; ++o) stab[o] = (stab[o] / ss) * tabular[o];
    }
    __syncthreads();
    float img = simg;
    float a0 = 0.f, a1 = 0.f;
    for (int j = tid; j < D1 + TDIM; j += 256) {
        float w = (j < D1) ? img * sM[j] : stab[j - D1];
        a0 += w * W_cls[j * 2 + 0];
        a1 += w * W_cls[j * 2 + 1];
    }
    red0[tid] = a0; red1[tid] = a1;
    __syncthreads();
    for (int o = 128; o > 0; o >>= 1) {
        if (tid < o) { red0[tid] += red0[tid + o]; red1[tid] += red1[tid + o]; }
        __syncthreads();
    }
    if (tid == 0) {
        float l0 = red0[0] + b_cls[0];
        float l1 = red1[0] + b_cls[1];
        d_out[0] = l0; d_out[1] = l1;
        float mx = fmaxf(l0, l1);
        float e0 = expf(l0 - mx), e1 = expf(l1 - mx);
        d_out[2] = e0 / (e0 + e1);
        d_out[3] = e1 / (e0 + e1);
        d_out[4] = (l1 > l0) ? 1.f : 0.f;
    }
}

extern "C" void kernel_launch(void* const* d_in, const int* in_sizes, int n_in,
                              void* d_out, int out_size, void* d_ws, size_t ws_size,
                              hipStream_t stream) {
    const float* h       = (const float*)d_in[0];
    const float* tabular = (const float*)d_in[1];
    const int*   label   = (const int*)d_in[2];
    const float* W_fc    = (const float*)d_in[3];
    const float* b_fc    = (const float*)d_in[4];
    const float* Wa      = (const float*)d_in[5];
    const float* ba      = (const float*)d_in[6];
    const float* Wb      = (const float*)d_in[7];
    const float* bb      = (const float*)d_in[8];
    const float* Wc      = (const float*)d_in[9];
    const float* bc      = (const float*)d_in[10];
    const float* W_inst  = (const float*)d_in[11];
    const float* b_inst  = (const float*)d_in[12];
    const float* W_img   = (const float*)d_in[13];
    const float* b_img   = (const float*)d_in[14];
    const float* W_tab   = (const float*)d_in[15];
    const float* b_tab   = (const float*)d_in[16];
    const float* W_cls   = (const float*)d_in[17];
    const float* b_cls   = (const float*)d_in[18];
    float* out = (float*)d_out;

    // workspace layout (~53 MB)
    u16* h512 = (u16*)d_ws;                          // NPAD x 512 bf16      (51.2 MB)
    u16* WfcT = h512 + (size_t)NPAD * D1;            // 512 x 1024 bf16      (1 MB)
    u16* WabT = WfcT + (size_t)D1 * LIN;             // 512 x 512 bf16 (gate-interleaved)
    u32* uarr = (u32*)(WabT + (size_t)2 * D2 * D1);  // NPAD sortable keys
    float* accum = (float*)(uarr + NPAD);            // [0]=Z, [8..520)=Mpart
    float* Zacc  = accum;
    float* Mpart = accum + 8;
    int* ids = (int*)(accum + 8 + D1);               // 128 selected indices
    int* ctl = ids + 128;                            // 16 ints: buckets+counters
    u32* hist = (u32*)(ctl + 16);                    // 65536 bins
    u32* cV0 = hist + NBIN;
    int* cI0 = (int*)(cV0 + CAND_MAX);
    u32* cV1 = (u32*)(cI0 + CAND_MAX);
    int* cI1 = (int*)(cV1 + CAND_MAX);

    pack_w<<<dim3(256), dim3(256), 0, stream>>>(W_fc, Wa, Wb, WfcT, WabT, (u32*)accum);
    gemm_fc<<<dim3(2, NPAD / 128), dim3(512), 0, stream>>>(h, WfcT, b_fc, h512);
    gemm_attn<<<dim3(NPAD / 64), dim3(512), 0, stream>>>(
        h512, WabT, ba, bb, Wc, bc, out + 5, uarr, hist, Zacc, Mpart);
    topk_collect<<<dim3(128), dim3(256), 0, stream>>>(hist, uarr, ctl, ids, cV0, cI0, cV1, cI1);
    tail_fused<<<dim3(1), dim3(256), 0, stream>>>(
        ctl, cV0, cI0, cV1, cI1, ids, h512, W_inst, b_inst, label,
        Mpart, Zacc, tabular, W_img, b_img, W_tab, b_tab, W_cls, b_cls, out);
}